// Round 14
// baseline (274.322 us; speedup 1.0000x reference)
//
#include <hip/hip_runtime.h>
#include <cstdint>

typedef unsigned short u16;
typedef short bf16x8_t __attribute__((ext_vector_type(8)));
typedef float f32x4_t __attribute__((ext_vector_type(4)));

#define DEVFN __device__ __forceinline__

DEVFN u16 f2bf(float f) {
  unsigned u = __builtin_bit_cast(unsigned, f);
  u = (u + 0x7fffu + ((u >> 16) & 1u)) >> 16;
  return (u16)u;
}
DEVFN float bf2f(u16 s) {
  unsigned u = ((unsigned)s) << 16;
  return __builtin_bit_cast(float, u);
}
DEVFN unsigned pk2bf(float a, float b) {
  return (unsigned)f2bf(a) | ((unsigned)f2bf(b) << 16);
}

// global -> LDS direct copy, 16B per lane; LDS dest linear in lane order.
DEVFN void gload_lds16(const u16* g, u16* l) {
  __builtin_amdgcn_global_load_lds(
      (const __attribute__((address_space(1))) void*)g,
      (__attribute__((address_space(3))) void*)l, 16, 0, 0);
}

// ---------------- prep: W transposes, W1@a vectors, deg histogram ----------------
__global__ void prep_kernel(const float* __restrict__ W1, const float* __restrict__ W2,
                            const float* __restrict__ a1s, const float* __restrict__ a1d,
                            const int* __restrict__ edst,
                            u16* __restrict__ w1t, u16* __restrict__ w2t,
                            float* __restrict__ ws1, float* __restrict__ wd1,
                            int* __restrict__ cnt, int e) {
  int b = blockIdx.x;
  if (b < 512) {
    int idx = b * 256 + threadIdx.x;
    int k = idx >> 9, m = idx & 511;
    w1t[m * 256 + k] = f2bf(W1[idx]);
  } else if (b < 640) {
    int idx = (b - 512) * 256 + threadIdx.x;
    int k = idx >> 6, m = idx & 63;
    w2t[m * 512 + k] = f2bf(W2[idx]);
  } else if (b < 648) {
    int b2 = b - 640;
    int h = b2 >> 1;
    int isD = b2 & 1;
    const float* av = (isD ? a1d : a1s) + h * 128;
    int k = threadIdx.x;
    float sum = 0.f;
#pragma unroll 8
    for (int d = 0; d < 128; ++d)
      sum = fmaf(W1[k * 512 + h * 128 + d], av[d], sum);
    (isD ? wd1 : ws1)[h * 256 + k] = sum;
  } else {
    int i = (b - 648) * 256 + threadIdx.x;
    if (i < e) atomicAdd(&cnt[edst[i]], 1);
  }
}

// ---------------- conv_alpha: x->bf16 + as1/ad1 = x . ws1/wd1 ----------------
__global__ __launch_bounds__(256) void conv_alpha_kernel(
    const float* __restrict__ x, const float* __restrict__ ws1, const float* __restrict__ wd1,
    u16* __restrict__ xb, float* __restrict__ as1, float* __restrict__ ad1, int n)
{
  int node = (blockIdx.x * 256 + threadIdx.x) >> 6;
  int lane = threadIdx.x & 63;
  if (node >= n) return;
  float4 xv = *reinterpret_cast<const float4*>(x + (size_t)node * 256 + lane * 4);
  uint2 pk;
  pk.x = pk2bf(xv.x, xv.y);
  pk.y = pk2bf(xv.z, xv.w);
  *reinterpret_cast<uint2*>(xb + (size_t)node * 256 + lane * 4) = pk;

  float p[8];
#pragma unroll
  for (int v = 0; v < 8; ++v) {
    const float* wv = (v < 4 ? ws1 : wd1) + (v & 3) * 256 + lane * 4;
    float4 w4 = *reinterpret_cast<const float4*>(wv);
    p[v] = xv.x * w4.x + xv.y * w4.y + xv.z * w4.z + xv.w * w4.w;
  }
#pragma unroll
  for (int d = 1; d < 64; d <<= 1) {
#pragma unroll
    for (int v = 0; v < 8; ++v) p[v] += __shfl_xor(p[v], d, 64);
  }
  if (lane == 0) {
    *reinterpret_cast<float4*>(as1 + (size_t)node * 4) = make_float4(p[0], p[1], p[2], p[3]);
    *reinterpret_cast<float4*>(ad1 + (size_t)node * 4) = make_float4(p[4], p[5], p[6], p[7]);
  }
}

// ---------------- CSR build ----------------
DEVFN int block_scan_256(int v, int tid, int* wsum) {
#pragma unroll
  for (int d = 1; d < 64; d <<= 1) {
    int u = __shfl_up(v, d, 64);
    if ((tid & 63) >= d) v += u;
  }
  if ((tid & 63) == 63) wsum[tid >> 6] = v;
  __syncthreads();
  int add = 0;
#pragma unroll
  for (int w = 0; w < 4; ++w) add += (w < (tid >> 6)) ? wsum[w] : 0;
  __syncthreads();
  return v + add;
}

__global__ __launch_bounds__(256) void scan_a_kernel(const int* __restrict__ cnt, int* __restrict__ bsum, int n) {
  __shared__ int ws4[4];
  int i = blockIdx.x * 256 + threadIdx.x;
  int v = (i < n) ? cnt[i] + 1 : 0;   // +1 self loop
  int incl = block_scan_256(v, threadIdx.x, ws4);
  if (threadIdx.x == 255) bsum[blockIdx.x] = incl;
}

__global__ __launch_bounds__(256) void scan_c_kernel(
    const int* __restrict__ cnt, const int* __restrict__ bsum,
    int* __restrict__ rowoff, int* __restrict__ cursor, int n)
{
  __shared__ int ws4[4];
  __shared__ int ws4b[4];
  __shared__ int base_sh;
  int pre = 0;
  for (int w = threadIdx.x; w < blockIdx.x; w += 256) pre += bsum[w];
#pragma unroll
  for (int d = 1; d < 64; d <<= 1) pre += __shfl_xor(pre, d, 64);
  if ((threadIdx.x & 63) == 0) ws4b[threadIdx.x >> 6] = pre;
  __syncthreads();
  if (threadIdx.x == 0) base_sh = ws4b[0] + ws4b[1] + ws4b[2] + ws4b[3];
  int i = blockIdx.x * 256 + threadIdx.x;
  int v = (i < n) ? cnt[i] + 1 : 0;
  int incl = block_scan_256(v, threadIdx.x, ws4);
  int off = base_sh + incl - v;
  if (i < n) {
    rowoff[i] = off;
    cursor[i] = off;
    if (i == n - 1) rowoff[n] = off + v;
  }
}

__global__ void scatter_kernel(const int* __restrict__ srcs, const int* __restrict__ dsts,
                               int* __restrict__ cursor, int* __restrict__ csr, int e, int n) {
  int i = blockIdx.x * 256 + threadIdx.x;
  if (i >= e + n) return;
  int s, d;
  if (i < e) { s = srcs[i]; d = dsts[i]; }
  else       { s = i - e; d = s; }
  int pos = atomicAdd(&cursor[d], 1);
  csr[pos] = s;
}

// ---------------- aggx: 4-head weighted x-aggregation, fused softmax ----------------
// Plane writes are NONTEMPORAL: written once, read exactly once by gemm1 which
// launches with zero gap. NT keeps the 100 MB stream out of the per-XCD L2s so
// gemm1's cross-XCD reads don't stall on dirty-line writeback.
__global__ __launch_bounds__(256) void aggx_kernel(
    const u16* __restrict__ xb, const float* __restrict__ as1,
    const float* __restrict__ ad1, const int* __restrict__ rowoff,
    const int* __restrict__ csr, u16* __restrict__ aggx, size_t plane, int n)
{
  int node = (blockIdx.x * 256 + threadIdx.x) >> 6;
  int lane = threadIdx.x & 63;
  if (node >= n) return;
  int e0 = rowoff[node], e1 = rowoff[node + 1];
  float4 adv = *reinterpret_cast<const float4*>(ad1 + (size_t)node * 4);
  const unsigned dimb = (unsigned)lane * 4;

  float acc[4][4];
#pragma unroll
  for (int h = 0; h < 4; ++h)
#pragma unroll
    for (int d = 0; d < 4; ++d) acc[h][d] = 0.f;
  float den[4] = {0.f, 0.f, 0.f, 0.f};

  for (int e = e0; e < e1; ++e) {
    unsigned s = (unsigned)csr[e];
    float4 a4 = *reinterpret_cast<const float4*>(as1 + ((size_t)s << 2));
    float ex[4];
    {
      float t0 = a4.x + adv.x, t1 = a4.y + adv.y, t2 = a4.z + adv.z, t3 = a4.w + adv.w;
      ex[0] = __expf(fmaxf(t0, 0.2f * t0));
      ex[1] = __expf(fmaxf(t1, 0.2f * t1));
      ex[2] = __expf(fmaxf(t2, 0.2f * t2));
      ex[3] = __expf(fmaxf(t3, 0.2f * t3));
    }
#pragma unroll
    for (int h = 0; h < 4; ++h) den[h] += ex[h];
    uint2 xv = *reinterpret_cast<const uint2*>(xb + (((size_t)s << 8) + dimb));
    float xf[4];
    xf[0] = bf2f((u16)(xv.x & 0xffffu));
    xf[1] = bf2f((u16)(xv.x >> 16));
    xf[2] = bf2f((u16)(xv.y & 0xffffu));
    xf[3] = bf2f((u16)(xv.y >> 16));
#pragma unroll
    for (int h = 0; h < 4; ++h)
#pragma unroll
      for (int d = 0; d < 4; ++d) acc[h][d] = fmaf(ex[h], xf[d], acc[h][d]);
  }

#pragma unroll
  for (int h = 0; h < 4; ++h) {
    float inv = 1.f / (den[h] + 1e-16f);
    unsigned lo = pk2bf(acc[h][0] * inv, acc[h][1] * inv);
    unsigned hi = pk2bf(acc[h][2] * inv, acc[h][3] * inv);
    unsigned long long o64 = (unsigned long long)lo | ((unsigned long long)hi << 32);
    __builtin_nontemporal_store(
        o64, reinterpret_cast<unsigned long long*>(aggx + (size_t)h * plane + ((size_t)node << 8) + dimb));
  }
}

// ================== GEMM1 (R11 config): BK=64, reg-staged A, XCD-grouped =======
// T2 swizzle (BK=64, 128B rows): slot' = slot ^ (row&7); read col ^= (rsel&7)*8.
// C (h1o) stores are NONTEMPORAL (written once, streamed by gemm2 next).
template<int BM, int BN, int WROWS, int K, int BK, int NP>
__global__ __launch_bounds__(256) void gemm1_kernel(
    const u16* __restrict__ Aall, const u16* __restrict__ BT,
    const float* __restrict__ b1, u16* __restrict__ C, int M, size_t plane)
{
  constexpr int WM = BM / WROWS;
  constexpr int MF = WM / 16;
  constexpr int NF = BN / 16;
  constexpr int KK = BK / 32;
  static_assert(BK == 64, "swizzle derived for 128B rows");
  __shared__ __align__(16) u16 sA[BM][BK];
  __shared__ __align__(16) u16 sB[BN][BK];

  const int tid = threadIdx.x;
  const int lane = tid & 63;
  const int wr = tid >> 6;

  const int bid = blockIdx.x;
  const int xcd = bid & 7;
  const int rest = bid >> 3;
  const int p = rest & (NP - 1);
  const int rb = rest / NP;
  const int r = rb * 8 + xcd;
  const int NRB = (M + BM - 1) / BM;
  if (r >= NRB) return;
  const int brow = r * BM;
  const int bcol = p * BN;
  const u16* A = Aall + (size_t)p * plane;

  f32x4_t acc[MF][NF];
#pragma unroll
  for (int i = 0; i < MF; ++i)
#pragma unroll
    for (int j = 0; j < NF; ++j) acc[i][j] = f32x4_t{0.f, 0.f, 0.f, 0.f};

  const int rsel = lane & 15;
  const int kgrp = (lane >> 4) * 8;
  const int rx = (rsel & 7) * 8;

#pragma unroll
  for (int k0 = 0; k0 < K; k0 += BK) {
    constexpr int RA = BM * BK / 2048;
    bf16x8_t av[RA];
#pragma unroll
    for (int c = 0; c < RA; ++c) {
      int t = c * 256 + tid;
      int row = t >> 3;
      int gr = brow + row; gr = gr < M ? gr : M - 1;
      av[c] = *reinterpret_cast<const bf16x8_t*>(A + (size_t)gr * K + k0 + (t & 7) * 8);
    }
#pragma unroll
    for (int c = 0; c < RA; ++c) {
      int t = c * 256 + tid;
      int row = t >> 3;
      int slot = (t & 7) ^ (row & 7);
      *reinterpret_cast<bf16x8_t*>(&sA[0][0] + row * BK + slot * 8) = av[c];
    }
    constexpr int RB = BN * BK / 2048;
#pragma unroll
    for (int c = 0; c < RB; ++c) {
      int t = c * 256 + tid;
      int row = t >> 3;
      int col = ((t & 7) ^ (row & 7)) * 8;
      gload_lds16(BT + (size_t)(bcol + row) * K + k0 + col, &sB[0][0] + t * 8);
    }
    __syncthreads();
#pragma unroll
    for (int kk = 0; kk < KK; ++kk) {
      const int cswz = (kk * 32 + kgrp) ^ rx;
      bf16x8_t af[MF], bfr[NF];
#pragma unroll
      for (int i = 0; i < MF; ++i) {
        int row = wr * WM + i * 16 + rsel;
        af[i] = *reinterpret_cast<const bf16x8_t*>(&sA[0][0] + row * BK + cswz);
      }
#pragma unroll
      for (int j = 0; j < NF; ++j) {
        int row = j * 16 + rsel;
        bfr[j] = *reinterpret_cast<const bf16x8_t*>(&sB[0][0] + row * BK + cswz);
      }
#pragma unroll
      for (int i = 0; i < MF; ++i)
#pragma unroll
        for (int j = 0; j < NF; ++j)
          acc[i][j] = __builtin_amdgcn_mfma_f32_16x16x32_bf16(af[i], bfr[j], acc[i][j], 0, 0, 0);
    }
    __syncthreads();
  }

  const int crow0 = (lane >> 4) * 4;
  const int ccol = lane & 15;
#pragma unroll
  for (int i = 0; i < MF; ++i)
#pragma unroll
    for (int j = 0; j < NF; ++j)
#pragma unroll
      for (int rr = 0; rr < 4; ++rr) {
        int gr = brow + wr * WM + i * 16 + crow0 + rr;
        int gc = bcol + j * 16 + ccol;
        if (gr < M) {
          float v = acc[i][j][rr] + b1[gc];
          v = v > 0.f ? v : (__expf(v) - 1.0f);   // ELU (abs err ~1e-7 << bf16 eps)
          __builtin_nontemporal_store(f2bf(v), &C[(size_t)gr * 512 + gc]);
        }
      }
}

// ---------------- GEMM2 (R11 config, swizzled gload_lds) + fused alpha2 dots ---
template<int BM, int BN, int WROWS, int K, int BK, int H, int DH>
__global__ __launch_bounds__(256) void gemm_alpha_kernel(
    const u16* __restrict__ A, const u16* __restrict__ BT, u16* __restrict__ C,
    const float* __restrict__ a_s, const float* __restrict__ a_d,
    float* __restrict__ as_out, float* __restrict__ ad_out, int M, int N)
{
  static_assert(BN == DH, "alpha store ownership");
  static_assert(BK == 64, "swizzle derived for 128B rows");
  constexpr int WM = BM / WROWS;
  constexpr int MF = WM / 16;
  constexpr int NF = BN / 16;
  constexpr int KK = BK / 32;
  __shared__ __align__(16) u16 sA[BM][BK];
  __shared__ __align__(16) u16 sB[BN][BK];

  const int tid = threadIdx.x;
  const int lane = tid & 63;
  const int wr = tid >> 6;
  const int brow = blockIdx.x * BM;
  const int bcol = blockIdx.y * BN;

  f32x4_t acc[MF][NF];
#pragma unroll
  for (int i = 0; i < MF; ++i)
#pragma unroll
    for (int j = 0; j < NF; ++j) acc[i][j] = f32x4_t{0.f, 0.f, 0.f, 0.f};

  const int rsel = lane & 15;
  const int kgrp = (lane >> 4) * 8;
  const int rx = (rsel & 7) * 8;

#pragma unroll
  for (int k0 = 0; k0 < K; k0 += BK) {
    constexpr int RA = BM * BK / 2048;
#pragma unroll
    for (int c = 0; c < RA; ++c) {
      int t = c * 256 + tid;
      int row = t >> 3;
      int col = ((t & 7) ^ (row & 7)) * 8;
      int gr = brow + row; gr = gr < M ? gr : M - 1;
      gload_lds16(A + (size_t)gr * K + k0 + col, &sA[0][0] + t * 8);
    }
    constexpr int RB = BN * BK / 2048;
#pragma unroll
    for (int c = 0; c < RB; ++c) {
      int t = c * 256 + tid;
      int row = t >> 3;
      int col = ((t & 7) ^ (row & 7)) * 8;
      gload_lds16(BT + (size_t)(bcol + row) * K + k0 + col, &sB[0][0] + t * 8);
    }
    __syncthreads();
#pragma unroll
    for (int kk = 0; kk < KK; ++kk) {
      const int cswz = (kk * 32 + kgrp) ^ rx;
      bf16x8_t af[MF], bfr[NF];
#pragma unroll
      for (int i = 0; i < MF; ++i) {
        int row = wr * WM + i * 16 + rsel;
        af[i] = *reinterpret_cast<const bf16x8_t*>(&sA[0][0] + row * BK + cswz);
      }
#pragma unroll
      for (int j = 0; j < NF; ++j) {
        int row = j * 16 + rsel;
        bfr[j] = *reinterpret_cast<const bf16x8_t*>(&sB[0][0] + row * BK + cswz);
      }
#pragma unroll
      for (int i = 0; i < MF; ++i)
#pragma unroll
        for (int j = 0; j < NF; ++j)
          acc[i][j] = __builtin_amdgcn_mfma_f32_16x16x32_bf16(af[i], bfr[j], acc[i][j], 0, 0, 0);
    }
    __syncthreads();
  }

  const int crow0 = (lane >> 4) * 4;
  const int ccol = lane & 15;

#pragma unroll
  for (int i = 0; i < MF; ++i)
#pragma unroll
    for (int j = 0; j < NF; ++j)
#pragma unroll
      for (int rr = 0; rr < 4; ++rr) {
        int gr = brow + wr * WM + i * 16 + crow0 + rr;
        int gc = bcol + j * 16 + ccol;
        if (gr < M) C[(size_t)gr * N + gc] = f2bf(acc[i][j][rr]);
      }

  const int head = bcol / DH;
  float asv[NF], adv[NF];
#pragma unroll
  for (int j = 0; j < NF; ++j) {
    int gc = bcol + j * 16 + ccol;
    asv[j] = a_s[gc];
    adv[j] = a_d[gc];
  }
#pragma unroll
  for (int i = 0; i < MF; ++i) {
#pragma unroll
    for (int rr = 0; rr < 4; ++rr) {
      float ps = 0.f, pd = 0.f;
#pragma unroll
      for (int j = 0; j < NF; ++j) {
        float v = acc[i][j][rr];
        ps = fmaf(v, asv[j], ps);
        pd = fmaf(v, adv[j], pd);
      }
#pragma unroll
      for (int d = 1; d < 16; d <<= 1) {
        ps += __shfl_xor(ps, d, 64);
        pd += __shfl_xor(pd, d, 64);
      }
      if ((lane & 15) == 0) {
        int gr = brow + wr * WM + i * 16 + crow0 + rr;
        if (gr < M) {
          as_out[(size_t)gr * H + head] = ps;
          ad_out[(size_t)gr * H + head] = pd;
        }
      }
    }
  }
}

// ---------------- agg2: half-wave per node, fused softmax ----------------
__global__ __launch_bounds__(256) void agg2_kernel(
    const u16* __restrict__ h2, const float* __restrict__ as2,
    const float* __restrict__ ad2, const int* __restrict__ rowoff,
    const int* __restrict__ csr, const float* __restrict__ b2,
    float* __restrict__ out, int n)
{
  int node = (blockIdx.x * 256 + threadIdx.x) >> 5;
  int l32 = threadIdx.x & 31;
  if (node >= n) return;
  int e0 = rowoff[node], e1 = rowoff[node + 1];
  float advn = ad2[node];

  float acc0 = 0.f, acc1 = 0.f, den = 0.f;
  for (int e = e0; e < e1; ++e) {
    unsigned s = (unsigned)csr[e];
    float t = as2[s] + advn;
    float l = fmaxf(t, 0.2f * t);
    float ex = __expf(l);
    den += ex;
    unsigned hv = *reinterpret_cast<const unsigned*>(h2 + (s << 6) + l32 * 2);
    acc0 = fmaf(ex, bf2f((u16)(hv & 0xffffu)), acc0);
    acc1 = fmaf(ex, bf2f((u16)(hv >> 16)), acc1);
  }
  float inv = 1.f / (den + 1e-16f);
  float2 o;
  o.x = acc0 * inv + b2[l32 * 2];
  o.y = acc1 * inv + b2[l32 * 2 + 1];
  *reinterpret_cast<float2*>(out + (((size_t)node) << 6) + l32 * 2) = o;
}

// ---------------- launch ----------------
extern "C" void kernel_launch(void* const* d_in, const int* in_sizes, int n_in,
                              void* d_out, int out_size, void* d_ws, size_t ws_size,
                              hipStream_t stream) {
  const float* x   = (const float*)d_in[0];
  const int*   ei  = (const int*)d_in[1];
  const float* W1  = (const float*)d_in[3];
  const float* a1s = (const float*)d_in[4];
  const float* a1d = (const float*)d_in[5];
  const float* b1  = (const float*)d_in[6];
  const float* W2  = (const float*)d_in[7];
  const float* a2s = (const float*)d_in[8];
  const float* a2d = (const float*)d_in[9];
  const float* b2  = (const float*)d_in[10];
  float* out = (float*)d_out;

  const int IN_DIM = 256, H1D1 = 512, D2 = 64;
  const int N = in_sizes[0] / IN_DIM;
  const int E = in_sizes[1] / 2;

  char* ws = (char*)d_ws;
  size_t off = 0;
  auto alloc = [&](size_t bytes) -> void* {
    void* p = ws + off;
    off += (bytes + 255) & ~(size_t)255;
    return p;
  };
  u16*  w1t    = (u16*)alloc((size_t)H1D1 * IN_DIM * 2);
  u16*  w2t    = (u16*)alloc((size_t)D2 * H1D1 * 2);
  float* ws1   = (float*)alloc(4 * 256 * 4);
  float* wd1   = (float*)alloc(4 * 256 * 4);
  u16*  xb     = (u16*)alloc((size_t)N * IN_DIM * 2);   // aliased by h2b/as2/ad2 later
  float* as1   = (float*)alloc((size_t)N * 4 * 4);
  float* ad1   = (float*)alloc((size_t)N * 4 * 4);
  int*  cnt    = (int*)alloc((size_t)N * 4);
  int*  cursor = (int*)alloc((size_t)N * 4);
  int*  rowoff = (int*)alloc((size_t)(N + 1) * 4);
  int*  bsum   = (int*)alloc(256 * 4);
  int*  csr    = (int*)alloc((size_t)(E + N) * 4);
  size_t plane = (size_t)N * IN_DIM;                    // u16 elems per head-plane
  u16*  aggx   = (u16*)alloc(4 * plane * 2);
  u16*  h1o    = (u16*)alloc((size_t)N * H1D1 * 2);
  (void)n_in; (void)out_size; (void)ws_size;

  // h2b/as2/ad2 alias the xb region: xb (25.6 MB) is dead after aggx, and
  // gemm2 (which writes h2b) runs strictly after aggx in-stream.
  u16*   h2b = xb;
  float* as2 = (float*)(xb + (size_t)N * D2);
  float* ad2 = as2 + N;

  const int* esrc = ei;
  const int* edst = ei + E;

  (void)hipMemsetAsync(cnt, 0, (size_t)N * 4, stream);

  int eb = (E + 255) / 256;
  prep_kernel<<<648 + eb, 256, 0, stream>>>(W1, W2, a1s, a1d, edst, w1t, w2t, ws1, wd1, cnt, E);

  conv_alpha_kernel<<<(N + 3) / 4, 256, 0, stream>>>(x, ws1, wd1, xb, as1, ad1, N);

  int nsb = (N + 255) / 256;
  scan_a_kernel<<<nsb, 256, 0, stream>>>(cnt, bsum, N);
  scan_c_kernel<<<nsb, 256, 0, stream>>>(cnt, bsum, rowoff, cursor, N);
  scatter_kernel<<<(E + N + 255) / 256, 256, 0, stream>>>(esrc, edst, cursor, csr, E, N);

  aggx_kernel<<<(N + 3) / 4, 256, 0, stream>>>(xb, as1, ad1, rowoff, csr, aggx, plane, N);

  // gemm1: XCD-grouped padded grid (R11 config), NP=4 panels
  const int NRB = (N + 127) / 128;
  const int g1 = ((NRB + 7) / 8) * 8 * 4;
  gemm1_kernel<128, 128, 4, 256, 64, 4><<<g1, 256, 0, stream>>>(aggx, w1t, b1, h1o, N, plane);

  dim3 g2((N + 63) / 64, 1);
  gemm_alpha_kernel<64, 64, 4, 512, 64, 1, 64><<<g2, 256, 0, stream>>>(
      h1o, w2t, h2b, a2s, a2d, as2, ad2, N, D2);

  agg2_kernel<<<((size_t)N * 32 + 255) / 256, 256, 0, stream>>>(h2b, as2, ad2, rowoff, csr, b2, out, N);
}

// Round 15
// 218.691 us; speedup vs baseline: 1.2544x; 1.2544x over previous
//
#include <hip/hip_runtime.h>
#include <cstdint>

typedef unsigned short u16;
typedef short bf16x8_t __attribute__((ext_vector_type(8)));
typedef float f32x4_t __attribute__((ext_vector_type(4)));

#define DEVFN __device__ __forceinline__

DEVFN u16 f2bf(float f) {
  unsigned u = __builtin_bit_cast(unsigned, f);
  u = (u + 0x7fffu + ((u >> 16) & 1u)) >> 16;
  return (u16)u;
}
DEVFN float bf2f(u16 s) {
  unsigned u = ((unsigned)s) << 16;
  return __builtin_bit_cast(float, u);
}
DEVFN unsigned pk2bf(float a, float b) {
  return (unsigned)f2bf(a) | ((unsigned)f2bf(b) << 16);
}

// global -> LDS direct copy, 16B per lane; LDS dest linear in lane order.
DEVFN void gload_lds16(const u16* g, u16* l) {
  __builtin_amdgcn_global_load_lds(
      (const __attribute__((address_space(1))) void*)g,
      (__attribute__((address_space(3))) void*)l, 16, 0, 0);
}

// ---------------- prep: W1/W2 transpose->bf16, deg histogram ----------------
__global__ void prep_kernel(const float* __restrict__ W1, const float* __restrict__ W2,
                            const int* __restrict__ edst,
                            u16* __restrict__ w1t, u16* __restrict__ w2t,
                            int* __restrict__ cnt, int e) {
  int b = blockIdx.x;
  if (b < 512) {                         // W1 [256][512] -> w1t [512][256]
    int idx = b * 256 + threadIdx.x;
    int k = idx >> 9, m = idx & 511;
    w1t[m * 256 + k] = f2bf(W1[idx]);
  } else if (b < 640) {                  // W2 [512][64] -> w2t [64][512]
    int idx = (b - 512) * 256 + threadIdx.x;
    int k = idx >> 6, m = idx & 63;
    w2t[m * 512 + k] = f2bf(W2[idx]);
  } else {                               // deg histogram
    int i = (b - 640) * 256 + threadIdx.x;
    if (i < e) atomicAdd(&cnt[edst[i]], 1);
  }
}

// ================= GEMM1: f32 A fused convert, swizzled LDS, XCD-grouped ======
// A[M][K] f32 @ BT[NP*BN][K] bf16 -> C[M][NP*BN] bf16 + fused alpha dots.
// The NP col-panel blocks sharing one A row-block get the same bid%8 (same XCD
// under round-robin dispatch) and adjacent slots -> A panel is fetched into
// that XCD's L2 once. T2 swizzle (BK=64, 128B rows): A reg-staged with
// swizzled ds_write slot; B gload_lds with pre-swizzled source column;
// reads XOR the same pattern. WCOLS==1: one wave owns an output row.
template<int BM, int BN, int WROWS, int K, int BK, int NP, int H, int DH>
__global__ __launch_bounds__(256) void gemm1_alpha_kernel(
    const float* __restrict__ A, const u16* __restrict__ BT, u16* __restrict__ C,
    const float* __restrict__ a_s, const float* __restrict__ a_d,
    float* __restrict__ as_out, float* __restrict__ ad_out, int M)
{
  constexpr int N = NP * BN;
  constexpr int WM = BM / WROWS;
  constexpr int MF = WM / 16;
  constexpr int NF = BN / 16;
  constexpr int KK = BK / 32;
  static_assert(BK == 64, "swizzle derived for 128B rows");
  __shared__ __align__(16) u16 sA[BM][BK];
  __shared__ __align__(16) u16 sB[BN][BK];

  const int tid = threadIdx.x;
  const int lane = tid & 63;
  const int wr = tid >> 6;

  const int bid = blockIdx.x;
  const int xcd = bid & 7;
  const int rest = bid >> 3;
  const int p = rest & (NP - 1);
  const int rb = rest / NP;
  const int r = rb * 8 + xcd;
  const int NRB = (M + BM - 1) / BM;
  if (r >= NRB) return;
  const int brow = r * BM;
  const int bcol = p * BN;

  f32x4_t acc[MF][NF];
#pragma unroll
  for (int i = 0; i < MF; ++i)
#pragma unroll
    for (int j = 0; j < NF; ++j) acc[i][j] = f32x4_t{0.f, 0.f, 0.f, 0.f};

  const int rsel = lane & 15;
  const int kgrp = (lane >> 4) * 8;
  const int rx = (rsel & 7) * 8;       // read-side XOR (u16 units)

#pragma unroll
  for (int k0 = 0; k0 < K; k0 += BK) {
    // stage A: f32 global -> regs -> bf16 pack -> swizzled ds_write_b128
    constexpr int RA = BM * BK / 2048;   // 4 rounds
#pragma unroll
    for (int c = 0; c < RA; ++c) {
      int t = c * 256 + tid;
      int row = t >> 3;
      int gr = brow + row; gr = gr < M ? gr : M - 1;
      const float* src = A + (size_t)gr * K + k0 + (t & 7) * 8;
      float4 v0 = *reinterpret_cast<const float4*>(src);
      float4 v1 = *reinterpret_cast<const float4*>(src + 4);
      uint4 pk;
      pk.x = pk2bf(v0.x, v0.y);
      pk.y = pk2bf(v0.z, v0.w);
      pk.z = pk2bf(v1.x, v1.y);
      pk.w = pk2bf(v1.z, v1.w);
      int slot = (t & 7) ^ (row & 7);
      *reinterpret_cast<uint4*>(&sA[0][0] + row * BK + slot * 8) = pk;
    }
    // stage B via global_load_lds with pre-swizzled source column (L2-hot)
    constexpr int RB = BN * BK / 2048;
#pragma unroll
    for (int c = 0; c < RB; ++c) {
      int t = c * 256 + tid;
      int row = t >> 3;
      int col = ((t & 7) ^ (row & 7)) * 8;
      gload_lds16(BT + (size_t)(bcol + row) * K + k0 + col, &sB[0][0] + t * 8);
    }
    __syncthreads();
#pragma unroll
    for (int kk = 0; kk < KK; ++kk) {
      const int cswz = (kk * 32 + kgrp) ^ rx;
      bf16x8_t af[MF], bfr[NF];
#pragma unroll
      for (int i = 0; i < MF; ++i) {
        int row = wr * WM + i * 16 + rsel;
        af[i] = *reinterpret_cast<const bf16x8_t*>(&sA[0][0] + row * BK + cswz);
      }
#pragma unroll
      for (int j = 0; j < NF; ++j) {
        int row = j * 16 + rsel;
        bfr[j] = *reinterpret_cast<const bf16x8_t*>(&sB[0][0] + row * BK + cswz);
      }
#pragma unroll
      for (int i = 0; i < MF; ++i)
#pragma unroll
        for (int j = 0; j < NF; ++j)
          acc[i][j] = __builtin_amdgcn_mfma_f32_16x16x32_bf16(af[i], bfr[j], acc[i][j], 0, 0, 0);
    }
    __syncthreads();
  }

  const int crow0 = (lane >> 4) * 4;
  const int ccol = lane & 15;

  // C write
#pragma unroll
  for (int i = 0; i < MF; ++i)
#pragma unroll
    for (int j = 0; j < NF; ++j)
#pragma unroll
      for (int rr = 0; rr < 4; ++rr) {
        int gr = brow + wr * WM + i * 16 + crow0 + rr;
        int gc = bcol + j * 16 + ccol;
        if (gr < M) C[(size_t)gr * N + gc] = f2bf(acc[i][j][rr]);
      }

  // fused alpha dots (1 wave owns a row; BN==DH so one block owns (row, head))
  const int head = bcol / DH;
  float asv[NF], adv[NF];
#pragma unroll
  for (int j = 0; j < NF; ++j) {
    int gc = bcol + j * 16 + ccol;
    asv[j] = a_s[gc];
    adv[j] = a_d[gc];
  }
#pragma unroll
  for (int i = 0; i < MF; ++i) {
#pragma unroll
    for (int rr = 0; rr < 4; ++rr) {
      float ps = 0.f, pd = 0.f;
#pragma unroll
      for (int j = 0; j < NF; ++j) {
        float v = acc[i][j][rr];
        ps = fmaf(v, asv[j], ps);
        pd = fmaf(v, adv[j], pd);
      }
#pragma unroll
      for (int d = 1; d < 16; d <<= 1) {
        ps += __shfl_xor(ps, d, 64);
        pd += __shfl_xor(pd, d, 64);
      }
      if ((lane & 15) == 0) {
        int gr = brow + wr * WM + i * 16 + crow0 + rr;
        if (gr < M) {
          as_out[(size_t)gr * H + head] = ps;
          ad_out[(size_t)gr * H + head] = pd;
        }
      }
    }
  }
}

// ---------------- GEMM2 (swizzled gload_lds, BK=64) + fused alpha2 dots -------
template<int BM, int BN, int WROWS, int K, int BK, int H, int DH>
__global__ __launch_bounds__(256) void gemm_alpha_kernel(
    const u16* __restrict__ A, const u16* __restrict__ BT, u16* __restrict__ C,
    const float* __restrict__ a_s, const float* __restrict__ a_d,
    float* __restrict__ as_out, float* __restrict__ ad_out, int M, int N)
{
  static_assert(BN == DH, "alpha store ownership");
  static_assert(BK == 64, "swizzle derived for 128B rows");
  constexpr int WM = BM / WROWS;
  constexpr int MF = WM / 16;
  constexpr int NF = BN / 16;
  constexpr int KK = BK / 32;
  __shared__ __align__(16) u16 sA[BM][BK];
  __shared__ __align__(16) u16 sB[BN][BK];

  const int tid = threadIdx.x;
  const int lane = tid & 63;
  const int wr = tid >> 6;
  const int brow = blockIdx.x * BM;
  const int bcol = blockIdx.y * BN;

  f32x4_t acc[MF][NF];
#pragma unroll
  for (int i = 0; i < MF; ++i)
#pragma unroll
    for (int j = 0; j < NF; ++j) acc[i][j] = f32x4_t{0.f, 0.f, 0.f, 0.f};

  const int rsel = lane & 15;
  const int kgrp = (lane >> 4) * 8;
  const int rx = (rsel & 7) * 8;

#pragma unroll
  for (int k0 = 0; k0 < K; k0 += BK) {
    constexpr int RA = BM * BK / 2048;
#pragma unroll
    for (int c = 0; c < RA; ++c) {
      int t = c * 256 + tid;
      int row = t >> 3;
      int col = ((t & 7) ^ (row & 7)) * 8;
      int gr = brow + row; gr = gr < M ? gr : M - 1;
      gload_lds16(A + (size_t)gr * K + k0 + col, &sA[0][0] + t * 8);
    }
    constexpr int RB = BN * BK / 2048;
#pragma unroll
    for (int c = 0; c < RB; ++c) {
      int t = c * 256 + tid;
      int row = t >> 3;
      int col = ((t & 7) ^ (row & 7)) * 8;
      gload_lds16(BT + (size_t)(bcol + row) * K + k0 + col, &sB[0][0] + t * 8);
    }
    __syncthreads();
#pragma unroll
    for (int kk = 0; kk < KK; ++kk) {
      const int cswz = (kk * 32 + kgrp) ^ rx;
      bf16x8_t af[MF], bfr[NF];
#pragma unroll
      for (int i = 0; i < MF; ++i) {
        int row = wr * WM + i * 16 + rsel;
        af[i] = *reinterpret_cast<const bf16x8_t*>(&sA[0][0] + row * BK + cswz);
      }
#pragma unroll
      for (int j = 0; j < NF; ++j) {
        int row = j * 16 + rsel;
        bfr[j] = *reinterpret_cast<const bf16x8_t*>(&sB[0][0] + row * BK + cswz);
      }
#pragma unroll
      for (int i = 0; i < MF; ++i)
#pragma unroll
        for (int j = 0; j < NF; ++j)
          acc[i][j] = __builtin_amdgcn_mfma_f32_16x16x32_bf16(af[i], bfr[j], acc[i][j], 0, 0, 0);
    }
    __syncthreads();
  }

  const int crow0 = (lane >> 4) * 4;
  const int ccol = lane & 15;

#pragma unroll
  for (int i = 0; i < MF; ++i)
#pragma unroll
    for (int j = 0; j < NF; ++j)
#pragma unroll
      for (int rr = 0; rr < 4; ++rr) {
        int gr = brow + wr * WM + i * 16 + crow0 + rr;
        int gc = bcol + j * 16 + ccol;
        if (gr < M) C[(size_t)gr * N + gc] = f2bf(acc[i][j][rr]);
      }

  const int head = bcol / DH;
  float asv[NF], adv[NF];
#pragma unroll
  for (int j = 0; j < NF; ++j) {
    int gc = bcol + j * 16 + ccol;
    asv[j] = a_s[gc];
    adv[j] = a_d[gc];
  }
#pragma unroll
  for (int i = 0; i < MF; ++i) {
#pragma unroll
    for (int rr = 0; rr < 4; ++rr) {
      float ps = 0.f, pd = 0.f;
#pragma unroll
      for (int j = 0; j < NF; ++j) {
        float v = acc[i][j][rr];
        ps = fmaf(v, asv[j], ps);
        pd = fmaf(v, adv[j], pd);
      }
#pragma unroll
      for (int d = 1; d < 16; d <<= 1) {
        ps += __shfl_xor(ps, d, 64);
        pd += __shfl_xor(pd, d, 64);
      }
      if ((lane & 15) == 0) {
        int gr = brow + wr * WM + i * 16 + crow0 + rr;
        if (gr < M) {
          as_out[(size_t)gr * H + head] = ps;
          ad_out[(size_t)gr * H + head] = pd;
        }
      }
    }
  }
}

// ---------------- CSR build ----------------
DEVFN int block_scan_256(int v, int tid, int* wsum) {
#pragma unroll
  for (int d = 1; d < 64; d <<= 1) {
    int u = __shfl_up(v, d, 64);
    if ((tid & 63) >= d) v += u;
  }
  if ((tid & 63) == 63) wsum[tid >> 6] = v;
  __syncthreads();
  int add = 0;
#pragma unroll
  for (int w = 0; w < 4; ++w) add += (w < (tid >> 6)) ? wsum[w] : 0;
  __syncthreads();
  return v + add;
}

__global__ __launch_bounds__(256) void scan_a_kernel(const int* __restrict__ cnt, int* __restrict__ bsum, int n) {
  __shared__ int ws4[4];
  int i = blockIdx.x * 256 + threadIdx.x;
  int v = (i < n) ? cnt[i] + 1 : 0;   // +1 self loop
  int incl = block_scan_256(v, threadIdx.x, ws4);
  if (threadIdx.x == 255) bsum[blockIdx.x] = incl;
}

__global__ __launch_bounds__(256) void scan_c_kernel(
    const int* __restrict__ cnt, const int* __restrict__ bsum,
    int* __restrict__ rowoff, int* __restrict__ cursor, int n)
{
  __shared__ int ws4[4];
  __shared__ int ws4b[4];
  __shared__ int base_sh;
  int pre = 0;
  for (int w = threadIdx.x; w < blockIdx.x; w += 256) pre += bsum[w];
#pragma unroll
  for (int d = 1; d < 64; d <<= 1) pre += __shfl_xor(pre, d, 64);
  if ((threadIdx.x & 63) == 0) ws4b[threadIdx.x >> 6] = pre;
  __syncthreads();
  if (threadIdx.x == 0) base_sh = ws4b[0] + ws4b[1] + ws4b[2] + ws4b[3];
  int i = blockIdx.x * 256 + threadIdx.x;
  int v = (i < n) ? cnt[i] + 1 : 0;
  int incl = block_scan_256(v, threadIdx.x, ws4);
  int off = base_sh + incl - v;
  if (i < n) {
    rowoff[i] = off;
    cursor[i] = off;
    if (i == n - 1) rowoff[n] = off + v;
  }
}

__global__ void scatter_kernel(const int* __restrict__ srcs, const int* __restrict__ dsts,
                               int* __restrict__ cursor, int* __restrict__ csr, int e, int n) {
  int i = blockIdx.x * 256 + threadIdx.x;
  if (i >= e + n) return;
  int s, d;
  if (i < e) { s = srcs[i]; d = dsts[i]; }
  else       { s = i - e; d = s; }
  int pos = atomicAdd(&cursor[d], 1);
  csr[pos] = s;
}

// ---------------- agg1: gather h1b, fused softmax (no-max-shift), b1+ELU -------
// one wave per dst node; lane covers dims [lane*8,lane*8+8), head=lane>>4.
__global__ __launch_bounds__(256) void agg1_kernel(
    const u16* __restrict__ h1, const float* __restrict__ as1,
    const float* __restrict__ ad1, const int* __restrict__ rowoff,
    const int* __restrict__ csr, const float* __restrict__ b1,
    u16* __restrict__ out, int n)
{
  int node = (blockIdx.x * 256 + threadIdx.x) >> 6;
  int lane = threadIdx.x & 63;
  if (node >= n) return;
  const unsigned head = lane >> 4;
  const unsigned dimbase = lane * 8;
  int e0 = rowoff[node], e1 = rowoff[node + 1];
  float advn = ad1[((unsigned)node << 2) + head];

  float acc[8];
#pragma unroll
  for (int j = 0; j < 8; ++j) acc[j] = 0.f;
  float den = 0.f;

  for (int e = e0; e < e1; ++e) {
    unsigned s = (unsigned)csr[e];
    float t = as1[(s << 2) + head] + advn;
    float l = fmaxf(t, 0.2f * t);          // leaky_relu, branchless
    float ex = __expf(l);
    den += ex;
    bf16x8_t hv = *reinterpret_cast<const bf16x8_t*>(h1 + ((s << 9) + dimbase));
#pragma unroll
    for (int j = 0; j < 8; ++j) acc[j] = fmaf(ex, bf2f((u16)hv[j]), acc[j]);
  }

  float inv = 1.f / (den + 1e-16f);
  u16* orow = out + (((unsigned)node << 9) + dimbase);
#pragma unroll
  for (int j = 0; j < 8; ++j) {
    float v = acc[j] * inv + b1[dimbase + j];
    v = v > 0.f ? v : (__expf(v) - 1.0f);   // ELU (abs err ~1e-7 << bf16 eps)
    orow[j] = f2bf(v);
  }
}

// ---------------- agg2: half-wave per node, fused softmax ----------------
__global__ __launch_bounds__(256) void agg2_kernel(
    const u16* __restrict__ h2, const float* __restrict__ as2,
    const float* __restrict__ ad2, const int* __restrict__ rowoff,
    const int* __restrict__ csr, const float* __restrict__ b2,
    float* __restrict__ out, int n)
{
  int node = (blockIdx.x * 256 + threadIdx.x) >> 5;
  int l32 = threadIdx.x & 31;
  if (node >= n) return;
  int e0 = rowoff[node], e1 = rowoff[node + 1];
  float advn = ad2[node];

  float acc0 = 0.f, acc1 = 0.f, den = 0.f;
  for (int e = e0; e < e1; ++e) {
    unsigned s = (unsigned)csr[e];
    float t = as2[s] + advn;
    float l = fmaxf(t, 0.2f * t);
    float ex = __expf(l);
    den += ex;
    unsigned hv = *reinterpret_cast<const unsigned*>(h2 + (s << 6) + l32 * 2);
    acc0 = fmaf(ex, bf2f((u16)(hv & 0xffffu)), acc0);
    acc1 = fmaf(ex, bf2f((u16)(hv >> 16)), acc1);
  }
  float inv = 1.f / (den + 1e-16f);
  float2 o;
  o.x = acc0 * inv + b2[l32 * 2];
  o.y = acc1 * inv + b2[l32 * 2 + 1];
  *reinterpret_cast<float2*>(out + (((size_t)node) << 6) + l32 * 2) = o;
}

// ---------------- launch ----------------
extern "C" void kernel_launch(void* const* d_in, const int* in_sizes, int n_in,
                              void* d_out, int out_size, void* d_ws, size_t ws_size,
                              hipStream_t stream) {
  const float* x   = (const float*)d_in[0];
  const int*   ei  = (const int*)d_in[1];
  const float* W1  = (const float*)d_in[3];
  const float* a1s = (const float*)d_in[4];
  const float* a1d = (const float*)d_in[5];
  const float* b1  = (const float*)d_in[6];
  const float* W2  = (const float*)d_in[7];
  const float* a2s = (const float*)d_in[8];
  const float* a2d = (const float*)d_in[9];
  const float* b2  = (const float*)d_in[10];
  float* out = (float*)d_out;

  const int IN_DIM = 256, H1D1 = 512, D2 = 64;
  const int N = in_sizes[0] / IN_DIM;
  const int E = in_sizes[1] / 2;

  char* ws = (char*)d_ws;
  size_t off = 0;
  auto alloc = [&](size_t bytes) -> void* {
    void* p = ws + off;
    off += (bytes + 255) & ~(size_t)255;
    return p;
  };
  u16*  w1t    = (u16*)alloc((size_t)H1D1 * IN_DIM * 2);
  u16*  w2t    = (u16*)alloc((size_t)D2 * H1D1 * 2);
  u16*  h1b    = (u16*)alloc((size_t)N * H1D1 * 2);
  int*  cnt    = (int*)alloc((size_t)N * 4);
  float* as1   = (float*)alloc((size_t)N * 4 * 4);
  float* ad1   = (float*)alloc((size_t)N * 4 * 4);
  float* as2   = (float*)alloc((size_t)N * 4);
  float* ad2   = (float*)alloc((size_t)N * 4);
  int*  cursor = (int*)alloc((size_t)N * 4);
  int*  rowoff = (int*)alloc((size_t)(N + 1) * 4);
  int*  bsum   = (int*)alloc(256 * 4);
  int*  csr    = (int*)alloc((size_t)(E + N) * 4);
  u16*  h1o    = (u16*)alloc((size_t)N * H1D1 * 2);
  u16*  h2b    = (u16*)alloc((size_t)N * D2 * 2);
  (void)n_in; (void)out_size; (void)ws_size;

  const int* esrc = ei;
  const int* edst = ei + E;

  (void)hipMemsetAsync(cnt, 0, (size_t)N * 4, stream);

  int eb = (E + 255) / 256;
  prep_kernel<<<640 + eb, 256, 0, stream>>>(W1, W2, edst, w1t, w2t, cnt, E);

  // gemm1: BM=128, NP=4 col-panels, XCD-grouped padded grid
  const int NRB = (N + 127) / 128;
  const int g1 = ((NRB + 7) / 8) * 8 * 4;
  gemm1_alpha_kernel<128, 128, 4, 256, 64, 4, 4, 128><<<g1, 256, 0, stream>>>(
      x, w1t, h1b, a1s, a1d, as1, ad1, N);

  int nsb = (N + 255) / 256;
  scan_a_kernel<<<nsb, 256, 0, stream>>>(cnt, bsum, N);
  scan_c_kernel<<<nsb, 256, 0, stream>>>(cnt, bsum, rowoff, cursor, N);
  scatter_kernel<<<(E + N + 255) / 256, 256, 0, stream>>>(esrc, edst, cursor, csr, E, N);

  agg1_kernel<<<(N + 3) / 4, 256, 0, stream>>>(h1b, as1, ad1, rowoff, csr, b1, h1o, N);

  dim3 g2((N + 63) / 64, 1);
  gemm_alpha_kernel<64, 64, 4, 512, 64, 1, 64><<<g2, 256, 0, stream>>>(
      h1o, w2t, h2b, a2s, a2d, as2, ad2, N, D2);

  agg2_kernel<<<((size_t)N * 32 + 255) / 256, 256, 0, stream>>>(h2b, as2, ad2, rowoff, csr, b2, out, N);
}